// Round 7
// baseline (82.472 us; speedup 1.0000x reference)
//
#include <hip/hip_runtime.h>
#include <math.h>

// B=64, C=256, HW=256, HEADS=8, HEAD_DIM=256, HID=2048, TEMB=512
// Identity: einsum 'bhnm,bhcl->bhml' contracts n,c independently =>
// softmaxes sum to 1 => q,k irrelevant; pre-projection output is
// SC^2 * colsum of v, constant over spatial l.
//
// Structure (R6 lesson: agent-scope grid barriers cost ~13-15us each due to
// per-XCD L2 flush/invalidate; avoid entirely):
//   K1 (96 blocks): scsh[b][512] time-MLP + Wv[8][256] v-colsums. ~2us.
//   K2 (64 blocks, one per b): coef -> x-pass -> of (in LDS) -> projection
//      -> RMS -> out = x + g. Fully per-b independent, no sync.

static constexpr float EPSV = 1e-6f;
static constexpr float SC2 = 1.0f / 256.0f;   // SC^2, SC = 256^-0.5

__device__ __forceinline__ float wave_sum(float v) {
    v += __shfl_xor(v, 1);  v += __shfl_xor(v, 2);
    v += __shfl_xor(v, 4);  v += __shfl_xor(v, 8);
    v += __shfl_xor(v, 16); v += __shfl_xor(v, 32);
    return v;
}

// ---------------- K1: time-MLP + Wv column-sums -------------------------
// blk<64 : scsh[b][j] = silu(temb[b]).mlp_w[j] + mlp_b[j]  (lane = t)
// blk>=64: w=blk-64 -> (h = w>>2, cq = w&3): Wv[h][cq*64..+63] full colsum
__global__ void __launch_bounds__(512) k1_prep(
    const float* __restrict__ temb, const float* __restrict__ mlp_w,
    const float* __restrict__ mlp_b, const float* __restrict__ qkv_w,
    float* __restrict__ scsh, float* __restrict__ wvg)
{
    __shared__ float sm[512];
    const int blk = blockIdx.x, tid = threadIdx.x;
    const int wv = tid >> 6, lane = tid & 63;
    if (blk < 64) {
        int b = blk;
        float v = temb[b * 512 + tid];
        sm[tid] = v / (1.0f + expf(-v));
        __syncthreads();
        for (int jj = 0; jj < 64; ++jj) {
            int j = wv * 64 + jj;
            const float* wr = mlp_w + (size_t)j * 512;
            float a0 = 0.f, a1 = 0.f;
#pragma unroll
            for (int k = 0; k < 8; k += 2) {
                a0 = fmaf(wr[(k + 0) * 64 + lane], sm[(k + 0) * 64 + lane], a0);
                a1 = fmaf(wr[(k + 1) * 64 + lane], sm[(k + 1) * 64 + lane], a1);
            }
            float a = wave_sum(a0 + a1);
            if (lane == 0) scsh[b * 512 + j] = a + mlp_b[j];
        }
    } else {
        int w = blk - 64;                  // 0..31
        int h = w >> 2, cq = w & 3;
        int cl = tid & 63, rp = tid >> 6;  // 8 row-parts x 32 rows
        const float* base =
            qkv_w + (size_t)(4096 + h * 256 + rp * 32) * 256 + cq * 64 + cl;
        float s = 0.f;
#pragma unroll
        for (int r = 0; r < 32; ++r) s += base[(size_t)r * 256];
        sm[rp * 64 + cl] = s;
        __syncthreads();
        if (tid < 64) {
            float t = 0.f;
#pragma unroll
            for (int r = 0; r < 8; ++r) t += sm[r * 64 + tid];
            wvg[h * 256 + cq * 64 + tid] = t;
        }
    }
}

// ---------------- K2: per-b full pipeline, 1024 threads ------------------
__global__ void __launch_bounds__(1024) k2_main(
    const float* __restrict__ x, const float* __restrict__ scsh,
    const float* __restrict__ wvg, const float* __restrict__ out_w,
    const float* __restrict__ out_b, const float* __restrict__ onorm,
    float* __restrict__ out)
{
    const int b = blockIdx.x, tid = threadIdx.x;
    const int wv = tid >> 6, lane = tid & 63;

    __shared__ float coef[256 * 8];        // [c][h]          8 KB
    __shared__ float apart[4 * 256 * 9];   // [cg][m][A0..7,ss2] 36 KB
    __shared__ float ofl[2048];            // of[h*256+m]     8 KB
    __shared__ float ssh[8];
    __shared__ float parts[4 * 8];
    __shared__ float yl[256];
    __shared__ float gl[256];
    __shared__ float wred[4];

    // ---- coef[c][h] = (1+scale[c])*Wv[h][c]; ssh[h] = sum_c shift*Wv ----
    if (tid < 256) {
        int c = tid;
        float sc = 1.0f + scsh[b * 512 + c];
        float sh = scsh[b * 512 + 256 + c];
#pragma unroll
        for (int h = 0; h < 8; ++h) {
            float wvv = wvg[h * 256 + c];
            coef[c * 8 + h] = sc * wvv;
            float sv = wave_sum(sh * wvv);
            if (lane == 0) parts[wv * 8 + h] = sv;
        }
    }
    __syncthreads();
    if (tid < 8)
        ssh[tid] = parts[tid] + parts[8 + tid] + parts[16 + tid] + parts[24 + tid];

    // ---- x-pass: A[h][m] = sum_c x[c][m]*coef[c][h]; ss2[m] -------------
    {
        int m = tid & 255, cg = tid >> 8;  // 4 c-groups x 64 c
        float A[8] = {0, 0, 0, 0, 0, 0, 0, 0};
        float ss2 = 0.f;
        const float* xb = x + (size_t)b * 65536 + m;
#pragma unroll 4
        for (int ci = 0; ci < 64; ++ci) {
            int c = cg * 64 + ci;
            float xv = xb[(size_t)c * 256];
            ss2 = fmaf(xv, xv, ss2);
            const float4 c0 = *reinterpret_cast<const float4*>(&coef[c * 8]);
            const float4 c1 = *reinterpret_cast<const float4*>(&coef[c * 8 + 4]);
            A[0] = fmaf(xv, c0.x, A[0]); A[1] = fmaf(xv, c0.y, A[1]);
            A[2] = fmaf(xv, c0.z, A[2]); A[3] = fmaf(xv, c0.w, A[3]);
            A[4] = fmaf(xv, c1.x, A[4]); A[5] = fmaf(xv, c1.y, A[5]);
            A[6] = fmaf(xv, c1.z, A[6]); A[7] = fmaf(xv, c1.w, A[7]);
        }
        float* ap = apart + ((size_t)cg * 256 + m) * 9;
#pragma unroll
        for (int h = 0; h < 8; ++h) ap[h] = A[h];
        ap[8] = ss2;
    }
    __syncthreads();
    if (tid < 256) {
        int m = tid;
        float fin[9];
#pragma unroll
        for (int i = 0; i < 9; ++i)
            fin[i] = apart[(0 * 256 + m) * 9 + i] + apart[(1 * 256 + m) * 9 + i] +
                     apart[(2 * 256 + m) * 9 + i] + apart[(3 * 256 + m) * 9 + i];
        float inv = rsqrtf(fin[8] * (1.0f / 256.0f) + EPSV);
#pragma unroll
        for (int h = 0; h < 8; ++h)
            ofl[h * 256 + m] = SC2 * fmaf(inv, fin[h], ssh[h]);
    }
    __syncthreads();

    // ---- projection: y[c] = out_b[c] + sum_o ofl[o]*out_w[c][o] ---------
    // wave wv owns c = wv*16..+15; lane = o (coalesced out_w rows)
#pragma unroll 2
    for (int cc = 0; cc < 16; ++cc) {
        int c = wv * 16 + cc;
        const float* wr = out_w + (size_t)c * 2048;
        float a0 = 0.f, a1 = 0.f;
#pragma unroll
        for (int k = 0; k < 32; k += 2) {
            a0 = fmaf(wr[(k + 0) * 64 + lane], ofl[(k + 0) * 64 + lane], a0);
            a1 = fmaf(wr[(k + 1) * 64 + lane], ofl[(k + 1) * 64 + lane], a1);
        }
        float a = wave_sum(a0 + a1);
        if (lane == 0) yl[c] = a + out_b[c];
    }
    __syncthreads();

    // ---- RMS over c + g --------------------------------------------------
    if (tid < 256) {
        float yb = yl[tid];
        float v2 = wave_sum(yb * yb);
        if (lane == 0) wred[wv] = v2;
    }
    __syncthreads();
    {
        float inv2 = rsqrtf((wred[0] + wred[1] + wred[2] + wred[3]) *
                            (1.0f / 256.0f) + EPSV);
        if (tid < 256) gl[tid] = yl[tid] * inv2 * onorm[tid];
    }
    __syncthreads();

    // ---- stream: out[b,c,hw] = x[b,c,hw] + g[c] --------------------------
    const float4* xx = reinterpret_cast<const float4*>(x) + (size_t)b * 16384;
    float4* oo = reinterpret_cast<float4*>(out) + (size_t)b * 16384;
#pragma unroll
    for (int i = tid; i < 16384; i += 1024) {
        int row = i >> 6;                  // 64 float4 per channel row
        float4 xv = xx[i];
        float gg = gl[row];
        oo[i] = make_float4(xv.x + gg, xv.y + gg, xv.z + gg, xv.w + gg);
    }
}

extern "C" void kernel_launch(void* const* d_in, const int* in_sizes, int n_in,
                              void* d_out, int out_size, void* d_ws, size_t ws_size,
                              hipStream_t stream) {
    const float* x     = (const float*)d_in[0];
    const float* temb  = (const float*)d_in[1];
    const float* mlp_w = (const float*)d_in[2];
    const float* mlp_b = (const float*)d_in[3];
    const float* qkv_w = (const float*)d_in[4];
    const float* out_w = (const float*)d_in[5];
    const float* out_b = (const float*)d_in[6];
    const float* onorm = (const float*)d_in[7];
    float* out = (float*)d_out;
    float* ws  = (float*)d_ws;

    float* scsh = ws;            // [64 b][512 j]  32768 floats
    float* wvg  = ws + 32768;    // [8 h][256 c]   2048 floats

    k1_prep<<<96, 512,  0, stream>>>(temb, mlp_w, mlp_b, qkv_w, scsh, wvg);
    k2_main<<<64, 1024, 0, stream>>>(x, scsh, wvg, out_w, out_b, onorm, out);
}

// Round 8
// 35.017 us; speedup vs baseline: 2.3552x; 2.3552x over previous
//
#include <hip/hip_runtime.h>
#include <math.h>

// B=64, C=256, HW=256, HEADS=8, HEAD_DIM=256, HID=2048, TEMB=512
// Identity: einsum 'bhnm,bhcl->bhml' contracts n,c independently =>
// softmaxes sum to 1 => q,k irrelevant; pre-projection output is
// SC^2 * colsum of v over head_dim, constant over spatial l.
//
// R7 lessons: (a) serial per-wave reduction loops are latency death
// (51us MLP at 24 VGPR, ~1900cy/iter); (b) per-b kernels cap streams at
// 64 CUs; (c) kernel boundaries are cheap, grid barriers are not.
// Structure: K0 prep (batched-j MLP + Wv colsums) -> K1 (b x m-quarter:
// x-pass + float4 projection partials) -> K2 (wide stream + tiny RMS).

static constexpr float EPSV = 1e-6f;
static constexpr float SC2 = 1.0f / 256.0f;   // SC^2, SC = 256^-0.5

__device__ __forceinline__ float wave_sum(float v) {
    v += __shfl_xor(v, 1);  v += __shfl_xor(v, 2);
    v += __shfl_xor(v, 4);  v += __shfl_xor(v, 8);
    v += __shfl_xor(v, 16); v += __shfl_xor(v, 32);
    return v;
}

// ---------------- K0: time-MLP + Wv column-sums -------------------------
// blk < 1024: (b, jg): 4 waves x 8 concurrent j => 32 j per block.
//   64 independent mlp_w loads in flight per thread, ONE wave_sum round.
// blk >= 1024: w = blk-1024: (h, cq): colsum of qkv_w v-block rows.
__global__ void __launch_bounds__(256) k0_prep(
    const float* __restrict__ temb, const float* __restrict__ mlp_w,
    const float* __restrict__ mlp_b, const float* __restrict__ qkv_w,
    float* __restrict__ scsh, float* __restrict__ wvg)
{
    const int blk = blockIdx.x, tid = threadIdx.x;
    const int wv = tid >> 6, lane = tid & 63;
    if (blk < 1024) {
        int b = blk >> 4, jg = blk & 15;
        __shared__ float sl[512];
        float v0 = temb[b * 512 + tid];
        float v1 = temb[b * 512 + 256 + tid];
        sl[tid] = v0 / (1.0f + expf(-v0));
        sl[256 + tid] = v1 / (1.0f + expf(-v1));
        __syncthreads();
        int j0 = jg * 32 + wv * 8;
        float acc[8] = {0, 0, 0, 0, 0, 0, 0, 0};
        const float* wb = mlp_w + (size_t)j0 * 512 + lane;
#pragma unroll
        for (int k = 0; k < 8; ++k) {
            float sv = sl[k * 64 + lane];
#pragma unroll
            for (int jj = 0; jj < 8; ++jj)
                acc[jj] = fmaf(wb[(size_t)jj * 512 + k * 64], sv, acc[jj]);
        }
#pragma unroll
        for (int jj = 0; jj < 8; ++jj) {
            float a = wave_sum(acc[jj]);
            if (lane == 0) scsh[b * 512 + j0 + jj] = a + mlp_b[j0 + jj];
        }
    } else {
        int w = blk - 1024;                // 0..31
        int h = w >> 2, cq = w & 3;
        __shared__ float sm[256];
        const float* base =
            qkv_w + (size_t)(4096 + h * 256 + wv * 64) * 256 + cq * 64 + lane;
        float s = 0.f;
#pragma unroll 8
        for (int r = 0; r < 64; ++r) s += base[(size_t)r * 256];
        sm[wv * 64 + lane] = s;
        __syncthreads();
        if (tid < 64)
            wvg[h * 256 + cq * 64 + tid] =
                sm[tid] + sm[64 + tid] + sm[128 + tid] + sm[192 + tid];
    }
}

// ---------------- K1: x-pass + projection partials ----------------------
// grid 256 = (b, q = m-quarter of 64); 1024 threads.
// of[h][m] for this quarter in LDS, then ypart[q][b][c] partial proj.
__global__ void __launch_bounds__(1024) k1_body(
    const float* __restrict__ x, const float* __restrict__ scsh,
    const float* __restrict__ wvg, const float* __restrict__ out_w,
    float* __restrict__ ypart)
{
    const int blk = blockIdx.x, tid = threadIdx.x;
    const int wv = tid >> 6, lane = tid & 63;
    const int b = blk >> 2, q = blk & 3;

    __shared__ float coef[256 * 8];        // [c][h]  8 KB
    __shared__ float apart[16 * 64 * 9];   // [cg][m][A0..7,ss2]  36 KB
    __shared__ float ofl[512];             // [h][m]  2 KB
    __shared__ float ssh[8];
    __shared__ float parts[4 * 8];

    // coef[c][h] = (1+scale[c])*Wv[h][c]; ssh[h] = sum_c shift[c]*Wv[h][c]
    if (tid < 256) {
        int c = tid;
        float sc = 1.0f + scsh[b * 512 + c];
        float sh = scsh[b * 512 + 256 + c];
#pragma unroll
        for (int h = 0; h < 8; ++h) {
            float wvv = wvg[h * 256 + c];
            coef[c * 8 + h] = sc * wvv;
            float sv = wave_sum(sh * wvv);
            if (lane == 0) parts[wv * 8 + h] = sv;
        }
    }
    __syncthreads();
    if (tid < 8)
        ssh[tid] = parts[tid] + parts[8 + tid] + parts[16 + tid] + parts[24 + tid];

    // x-pass: thread (m = tid&63, cg = tid>>6 of 16 c's)
    {
        int m = tid & 63, cg = tid >> 6;
        float A[8] = {0, 0, 0, 0, 0, 0, 0, 0};
        float ss2 = 0.f;
        const float* xb = x + (size_t)b * 65536 + q * 64 + m;
#pragma unroll
        for (int ci = 0; ci < 16; ++ci) {
            int c = cg * 16 + ci;
            float xv = xb[(size_t)c * 256];
            ss2 = fmaf(xv, xv, ss2);
            const float4 c0 = *reinterpret_cast<const float4*>(&coef[c * 8]);
            const float4 c1 = *reinterpret_cast<const float4*>(&coef[c * 8 + 4]);
            A[0] = fmaf(xv, c0.x, A[0]); A[1] = fmaf(xv, c0.y, A[1]);
            A[2] = fmaf(xv, c0.z, A[2]); A[3] = fmaf(xv, c0.w, A[3]);
            A[4] = fmaf(xv, c1.x, A[4]); A[5] = fmaf(xv, c1.y, A[5]);
            A[6] = fmaf(xv, c1.z, A[6]); A[7] = fmaf(xv, c1.w, A[7]);
        }
        float* ap = apart + ((size_t)(tid >> 6) * 64 + m) * 9;
#pragma unroll
        for (int h = 0; h < 8; ++h) ap[h] = A[h];
        ap[8] = ss2;
        (void)cg;
    }
    __syncthreads();
    if (tid < 64) {
        int m = tid;
        float fin[9] = {0, 0, 0, 0, 0, 0, 0, 0, 0};
#pragma unroll
        for (int g = 0; g < 16; ++g)
#pragma unroll
            for (int i = 0; i < 9; ++i)
                fin[i] += apart[((size_t)g * 64 + m) * 9 + i];
        float inv = rsqrtf(fin[8] * (1.0f / 256.0f) + EPSV);
#pragma unroll
        for (int h = 0; h < 8; ++h)
            ofl[h * 64 + m] = SC2 * fmaf(inv, fin[h], ssh[h]);
    }
    __syncthreads();

    // projection partial: y_q[c] = sum_{h,m in q} of[h][m]*out_w[c][h*256+q*64+m]
    // wave wv owns c = wv*16..+15, 4 concurrent; float4 over m.
    const float4* of4 = reinterpret_cast<const float4*>(ofl);   // [128]
#pragma unroll
    for (int g4 = 0; g4 < 4; ++g4) {
        int c0 = wv * 16 + g4 * 4;
        float a[4] = {0, 0, 0, 0};
#pragma unroll
        for (int cc = 0; cc < 4; ++cc) {
            int c = c0 + cc;
#pragma unroll
            for (int k = 0; k < 2; ++k) {
                int idx = k * 64 + lane;        // float4 idx 0..127
                int h = idx >> 4, mm = (idx & 15) * 4;
                const float4 w4 = *reinterpret_cast<const float4*>(
                    &out_w[(size_t)c * 2048 + h * 256 + q * 64 + mm]);
                float4 ov = of4[idx];
                a[cc] = fmaf(w4.x, ov.x, a[cc]);
                a[cc] = fmaf(w4.y, ov.y, a[cc]);
                a[cc] = fmaf(w4.z, ov.z, a[cc]);
                a[cc] = fmaf(w4.w, ov.w, a[cc]);
            }
        }
#pragma unroll
        for (int cc = 0; cc < 4; ++cc) {
            float s = wave_sum(a[cc]);
            if (lane == 0) ypart[(size_t)q * 16384 + b * 256 + c0 + cc] = s;
        }
    }
}

// ---------------- K2: reduce + RMS + g, wide stream ---------------------
// grid 2048 = (b, ch of 32); 256 thr. Redundant tiny per-b RMS, then
// out[b,c,hw] = x[b,c,hw] + g[c] at full-grid HBM BW.
__global__ void __launch_bounds__(256) k2_fin(
    const float* __restrict__ ypart, const float* __restrict__ out_b,
    const float* __restrict__ onorm, const float* __restrict__ x,
    float* __restrict__ out)
{
    const int blk = blockIdx.x, tid = threadIdx.x;
    const int b = blk >> 5, ch = blk & 31;
    __shared__ float gl[256];
    __shared__ float wred[4];
    float yb = out_b[tid] +
               ypart[b * 256 + tid] + ypart[16384 + b * 256 + tid] +
               ypart[32768 + b * 256 + tid] + ypart[49152 + b * 256 + tid];
    float v2 = wave_sum(yb * yb);
    if ((tid & 63) == 0) wred[tid >> 6] = v2;
    __syncthreads();
    float inv2 = rsqrtf((wred[0] + wred[1] + wred[2] + wred[3]) *
                        (1.0f / 256.0f) + EPSV);
    gl[tid] = yb * inv2 * onorm[tid];
    __syncthreads();

    const float4* xx = reinterpret_cast<const float4*>(x) +
                       (size_t)b * 16384 + ch * 512;
    float4* oo = reinterpret_cast<float4*>(out) + (size_t)b * 16384 + ch * 512;
#pragma unroll
    for (int k = 0; k < 2; ++k) {
        int i = k * 256 + tid;
        int row = (ch * 512 + i) >> 6;
        float4 xv = xx[i];
        float gg = gl[row];
        oo[i] = make_float4(xv.x + gg, xv.y + gg, xv.z + gg, xv.w + gg);
    }
}

extern "C" void kernel_launch(void* const* d_in, const int* in_sizes, int n_in,
                              void* d_out, int out_size, void* d_ws, size_t ws_size,
                              hipStream_t stream) {
    const float* x     = (const float*)d_in[0];
    const float* temb  = (const float*)d_in[1];
    const float* mlp_w = (const float*)d_in[2];
    const float* mlp_b = (const float*)d_in[3];
    const float* qkv_w = (const float*)d_in[4];
    const float* out_w = (const float*)d_in[5];
    const float* out_b = (const float*)d_in[6];
    const float* onorm = (const float*)d_in[7];
    float* out = (float*)d_out;
    float* ws  = (float*)d_ws;

    float* scsh  = ws;            // [64 b][512 j]       32768
    float* wvg   = ws + 32768;    // [8 h][256 c]        2048
    float* ypart = ws + 34816;    // [4 q][64 b][256 c]  65536

    k0_prep<<<1056, 256,  0, stream>>>(temb, mlp_w, mlp_b, qkv_w, scsh, wvg);
    k1_body<<<256,  1024, 0, stream>>>(x, scsh, wvg, out_w, ypart);
    k2_fin <<<2048, 256,  0, stream>>>(ypart, out_b, onorm, x, out);
}